// Round 14
// baseline (50.271 us; speedup 1.0000x reference)
//
#include <hip/hip_runtime.h>
#include <hip/hip_bf16.h>

// Problem constants (from reference)
#define BB 8
#define CC 64
#define OO 64
#define HH 128
#define WW 128
#define HP 130   // padded
#define WP 130
#define KP 9

typedef __attribute__((ext_vector_type(8))) _Float16 f16x8;
typedef __attribute__((ext_vector_type(2))) _Float16 h2;
typedef __attribute__((ext_vector_type(4))) float f32x4;
typedef __attribute__((ext_vector_type(4))) unsigned u32x4;

#define ROWB 16640u   // x_t row stride in bytes = WP*CC*2

static __device__ __forceinline__ unsigned short f2h(float f) {
  _Float16 h = (_Float16)f;
  return __builtin_bit_cast(unsigned short, h);
}
static __device__ __forceinline__ h2 asH2(unsigned u) {
  return __builtin_bit_cast(h2, u);
}
static __device__ __forceinline__ unsigned asU32(h2 v) {
  return __builtin_bit_cast(unsigned, v);
}

// ---------------------------------------------------------------------------
// Kernel 1: x [B][C][H][W] f32 -> x_t [B][HP][WP][C] f16, zero borders.
// XCD-swizzled so XCD k produces x_t[b=k] into its own L2.
// Blocks 0-143 also convert the weight tensor into MFMA B-fragments (merged
// former k_wfrag: one fewer launch).
// ---------------------------------------------------------------------------
__global__ __launch_bounds__(256) void k_xpose(const float* __restrict__ x,
                                               const float* __restrict__ wsrc,
                                               unsigned short* __restrict__ xt,
                                               unsigned short* __restrict__ wf) {
  __shared__ unsigned short tile[128][66];
  int wg0 = blockIdx.x;           // B*H = 1024
  int t = threadIdx.x;
  // merged wfrag chore (36864 elems over first 144 blocks)
  if (wg0 < 144) {
    int flat = wg0 * 256 + t;
    int j = flat & 7;
    int lane = (flat >> 3) & 63;
    int nf = (flat >> 9) & 3;
    int ks = (flat >> 11) & 1;
    int p = flat >> 12;
    int c = ks * 32 + ((lane >> 4) * 8) + j;
    int o = nf * 16 + (lane & 15);
    wf[flat] = f2h(wsrc[(size_t)(o * CC + c) * KP + p]);
  }
  int wg = (wg0 & 7) * 128 + (wg0 >> 3);   // XCD-chunked: XCD k gets b=k
  int h = wg & 127, b = wg >> 7;
  int w = t & 127, chalf = t >> 7;
  const float* xp = x + ((size_t)(b * CC) * HH + h) * WW;
#pragma unroll 4
  for (int c2 = 0; c2 < 32; ++c2) {
    int c = c2 * 2 + chalf;
    float v = xp[(size_t)c * HH * WW + w];
    tile[w][c] = f2h(v);
  }
  __syncthreads();
  int c = t & 63, w2 = t >> 6;
  unsigned short* xtb = xt + (size_t)b * HP * WP * CC;
#pragma unroll 4
  for (int w4 = 0; w4 < 32; ++w4) {
    int ww = w4 * 4 + w2;
    xtb[((size_t)(h + 1) * WP + (ww + 1)) * CC + c] = tile[ww][c];
  }
  if (t < 128) {
    int xx = (t >= 64) ? (WP - 1) : 0;
    xtb[((size_t)(h + 1) * WP + xx) * CC + (t & 63)] = 0;
  }
  if (h == 0) {
    for (int i = t; i < 2 * WP * CC; i += 256) {
      int top = (i < WP * CC);
      int rem = top ? i : i - WP * CC;
      size_t y = top ? 0 : (HP - 1);
      xtb[y * WP * CC + rem] = 0;
    }
  }
}

// ---------------------------------------------------------------------------
// Main kernel. 128-thread blocks (2 waves), grid 4096: one block =
// (b, h, 32-px tile) x all 64 outputs. Wave w owns outputs [32w, 32w+32)
// (2 nf x 2 m acc). Smaller blocks: LDS 10.5 KB -> ~13 blocks/CU headroom,
// barrier syncs only 2 waves. f16 sampling path (r13-proven).
// Queue ledger per p: [g8] +wf4 -> vmcnt(4) BUILD -> bar -> ISSUE(p+1)
// -> vmcnt(8) drains wf -> MFMA.  (p=8: vmcnt(0).)
// NO pressure-capping launch_bounds: allocator must never spill asm-load
// dsts (r7/r8 lesson).
// ---------------------------------------------------------------------------
__global__ __launch_bounds__(128) void k_deform_main(const float* __restrict__ offset,
                                                     const float* __restrict__ bias,
                                                     const unsigned short* __restrict__ xt,
                                                     const unsigned short* __restrict__ wf,
                                                     float* __restrict__ out) {
  __shared__ __align__(16) char lds[10496];
  // [0,8192)      S double buffer: 2 x (32 px * 128 B, XOR-swizzled rows)
  // [8192,10496)  coords: 2 waves * 144 entries * 8 B
  // epilogue reuses [0,8320) as S2: f32 [32][65]
  int wg0 = blockIdx.x;                    // 4096
  int wgs = (wg0 & 7) * 512 + (wg0 >> 3);  // XCD k -> b=k
  int tile = wgs & 3, h = (wgs >> 2) & 127, b = wgs >> 9;
  int w0 = tile * 32;
  int t = threadIdx.x, wave = t >> 6, lane = t & 63;

  char* S0 = lds;
  uint2* cw = reinterpret_cast<uint2*>(lds + 8192) + wave * 144;

  // ---- phase 1: coordinate precompute (144 (p,pxl) pairs / wave, 8B packed) ----
  // word0 = corner00 byte offset (22b) | dxflag<<30 | dyflag<<31
  // word1 = f16(wy1) | f16(wx1)<<16   (consumed directly as packed f16)
#pragma unroll
  for (int it = 0; it < 3; ++it) {
    int pair = it * 64 + lane;
    if (pair < 144) {
      int p = pair >> 4, pxl = pair & 15;
      int w = w0 + wave * 16 + pxl;
      const float* offp = offset + (((size_t)b * 18 + 2 * p) * HH + h) * WW + w;
      float offy = offp[0];
      float offx = offp[HH * WW];
      float cy = (float)(h + p / 3) + offy;
      float cx = (float)(w + p % 3) + offx;
      float y0f = floorf(cy), x0f = floorf(cx);
      float wy1 = cy - y0f, wx1 = cx - x0f;
      int iy0 = (int)y0f, ix0 = (int)x0f;
      int iy0c = min(max(iy0, 0), HP - 1);
      int iy1c = min(max(iy0 + 1, 0), HP - 1);
      int ix0c = min(max(ix0, 0), WP - 1);
      int ix1c = min(max(ix0 + 1, 0), WP - 1);
      unsigned w0p = (unsigned)((iy0c * WP + ix0c) * (CC * 2));
      if (ix1c != ix0c) w0p |= (1u << 30);
      if (iy1c != iy0c) w0p |= (1u << 31);
      unsigned hv;
      asm("v_cvt_pkrtz_f16_f32 %0, %1, %2" : "=v"(hv) : "v"(wy1), "v"(wx1));
      uint2 ce;
      ce.x = w0p;
      ce.y = hv;
      cw[pair] = ce;
    }
  }

  f32x4 acc[4];   // acc[m*2+nf]
#pragma unroll
  for (int m = 0; m < 4; ++m) acc[m] = (f32x4){0.f, 0.f, 0.f, 0.f};

  const char* xb = (const char*)(xt + (size_t)b * HP * WP * CC);
  int c8 = lane & 7, pg = lane >> 3;
  unsigned cb = (unsigned)c8 * 16;              // byte offset of this lane's 8 channels
  unsigned swz = cb ^ ((unsigned)pg << 4);      // write column (XOR row swizzle)
  const uint2* cwl = cw + pg;                   // + p*16 + it*8

#define GLOADX(dst, voff) \
  asm volatile("global_load_dwordx4 %0, %1, %2" \
               : "=v"(dst) : "v"(voff), "s"(xb) : "memory")
#define GLOADW(dst, voff) \
  asm volatile("global_load_dwordx4 %0, %1, %2" \
               : "=v"(dst) : "v"(voff), "s"(wf) : "memory")

  auto LOADC = [&](int p, uint2* eo) {
#pragma unroll
    for (int it = 0; it < 2; ++it) eo[it] = cwl[p * 16 + it * 8];
  };
  auto ISSUE = [&](const uint2* ei, u32x4* go) {
#pragma unroll
    for (int it = 0; it < 2; ++it) {
      unsigned w0p = ei[it].x;
      unsigned a00 = (w0p & 0x003FFFFFu) + cb;
      unsigned dx = ((w0p >> 30) & 1u) << 7;                  // 0 or 128 B (CC*2)
      unsigned dy = (w0p & 0x80000000u) ? ROWB : 0u;          // 0 or 16640
      unsigned a01 = a00 + dx, a10 = a00 + dy, a11 = a10 + dx;
      GLOADX(go[it * 4 + 0], a00);
      GLOADX(go[it * 4 + 1], a01);
      GLOADX(go[it * 4 + 2], a10);
      GLOADX(go[it * 4 + 3], a11);
    }
  };
  auto BUILD = [&](const uint2* ei, const u32x4* gi, char* Sc) {
    char* swave = Sc + wave * 2048 + pg * 128;
#pragma unroll
    for (int it = 0; it < 2; ++it) {
      h2 wyx = asH2(ei[it].y);                 // {wy1, wx1} as f16
      _Float16 wy = wyx.x, wx = wyx.y;
      _Float16 w11 = wy * wx;
      _Float16 w01 = wx - w11;                 // wx*(1-wy)
      _Float16 w10 = wy - w11;                 // wy*(1-wx)
      _Float16 w00 = (_Float16)1.0f - wx - w10;
      h2 W00 = {w00, w00}, W01 = {w01, w01}, W10 = {w10, w10}, W11 = {w11, w11};
      u32x4 q00 = gi[it * 4 + 0], q01 = gi[it * 4 + 1];
      u32x4 q10 = gi[it * 4 + 2], q11 = gi[it * 4 + 3];
      u32x4 pk;
#pragma unroll
      for (int k = 0; k < 4; ++k) {
        h2 s = W00 * asH2(q00[k]) + W01 * asH2(q01[k])
             + W10 * asH2(q10[k]) + W11 * asH2(q11[k]);   // v_pk_mul + 3 v_pk_fma
        pk[k] = asU32(s);
      }
      *reinterpret_cast<u32x4*>(swave + it * 1024 + swz) = pk;
    }
  };
  auto MFMA = [&](const char* Sc, f16x8 b00, f16x8 b01, f16x8 b10, f16x8 b11) {
    // bNK: N = nf within wave (o = wave*32 + N*16 + l15), K = ks
    int l15 = lane & 15, kc = (lane >> 4) * 16, sw = (lane & 7) << 4;
#pragma unroll
    for (int m = 0; m < 2; ++m) {
      int rb = (m * 16 + l15) * 128;
      f16x8 a0 = *reinterpret_cast<const f16x8*>(Sc + rb + (kc ^ sw));
      f16x8 a1 = *reinterpret_cast<const f16x8*>(Sc + rb + ((64 + kc) ^ sw));
      acc[m * 2 + 0] = __builtin_amdgcn_mfma_f32_16x16x32_f16(a0, b00, acc[m * 2 + 0], 0, 0, 0);
      acc[m * 2 + 0] = __builtin_amdgcn_mfma_f32_16x16x32_f16(a1, b01, acc[m * 2 + 0], 0, 0, 0);
      acc[m * 2 + 1] = __builtin_amdgcn_mfma_f32_16x16x32_f16(a0, b10, acc[m * 2 + 1], 0, 0, 0);
      acc[m * 2 + 1] = __builtin_amdgcn_mfma_f32_16x16x32_f16(a1, b11, acc[m * 2 + 1], 0, 0, 0);
    }
  };

  // ---- pipelined p-loop (r11-proven ledger, wf widened to 4) ----
  uint2 e[2];
  u32x4 g[8];
  LOADC(0, e);
  ISSUE(e, g);                     // queue [g8]
#pragma unroll
  for (int p = 0; p < 9; ++p) {
    char* Sc = S0 + (p & 1) * 4096;
    f16x8 bv00, bv01, bv10, bv11;
    // wf byte offset for (p, ks, nf_g = wave*2 + N): ((p*2+ks)*4 + nf_g)*1024 + lane*16
    unsigned wfo = (unsigned)((p * 8 + wave * 2) * 1024 + lane * 16);
    GLOADW(bv00, wfo);             // N=0 ks=0
    GLOADW(bv01, wfo + 4096);      // N=0 ks=1
    GLOADW(bv10, wfo + 1024);      // N=1 ks=0
    GLOADW(bv11, wfo + 5120);      // N=1 ks=1   queue [g8, wf4] = 12
    asm volatile("s_waitcnt vmcnt(4)" ::: "memory");   // drain g; wf flying
    __builtin_amdgcn_sched_barrier(0);
    BUILD(e, g, Sc);               // consumes g, writes own S slice
    if (p < 8) LOADC(p + 1, e);    // e dead after BUILD — reuse
    // S + coords visible; other wave's MFMA(p-1) LDS reads drained
    asm volatile("s_waitcnt lgkmcnt(0)" ::: "memory");
    __builtin_amdgcn_s_barrier();
    if (p < 8) {
      ISSUE(e, g);                 // queue [wf4, g8] = 12
      asm volatile("s_waitcnt vmcnt(8)" ::: "memory"); // drain wf
    } else {
      asm volatile("s_waitcnt vmcnt(0)" ::: "memory");
    }
    __builtin_amdgcn_sched_barrier(0);
    MFMA(Sc, bv00, bv01, bv10, bv11);
  }
#undef GLOADX
#undef GLOADW

  // ---- epilogue: LDS transpose for coalesced NCHW stores ----
  __syncthreads();  // all MFMA reads done before overwriting lds as S2
  float* S2 = reinterpret_cast<float*>(lds);
  int l15 = lane & 15;
#pragma unroll
  for (int m = 0; m < 2; ++m) {
#pragma unroll
    for (int nf = 0; nf < 2; ++nf) {
#pragma unroll
      for (int i2 = 0; i2 < 4; ++i2) {
        int px = m * 16 + ((lane >> 4) * 4) + i2;
        int o = wave * 32 + nf * 16 + l15;
        S2[px * 65 + o] = acc[m * 2 + nf][i2];
      }
    }
  }
  __syncthreads();
  {
    int px = t & 31, o2 = t >> 5;   // 4 o-lanes
    float* op = out + (((size_t)b * OO) * HH + h) * WW + w0 + px;
#pragma unroll
    for (int o4 = 0; o4 < 16; ++o4) {
      int o = o4 * 4 + o2;
      op[(size_t)o * HH * WW] = S2[px * 65 + o] + bias[o];
    }
  }
}

// ---------------------------------------------------------------------------
extern "C" void kernel_launch(void* const* d_in, const int* in_sizes, int n_in,
                              void* d_out, int out_size, void* d_ws, size_t ws_size,
                              hipStream_t stream) {
  const float* x = (const float*)d_in[0];
  const float* offset = (const float*)d_in[1];
  const float* weight = (const float*)d_in[2];
  const float* bias = (const float*)d_in[3];
  float* out = (float*)d_out;

  unsigned short* xt = (unsigned short*)d_ws;                       // 17,305,600 B
  unsigned short* wf = (unsigned short*)((char*)d_ws + 17305600);   //     73,728 B

  k_xpose<<<BB * HH, 256, 0, stream>>>(x, weight, xt, wf);
  k_deform_main<<<BB * HH * 4, 128, 0, stream>>>(offset, bias, xt, wf, out);
}

// Round 15
// 49.388 us; speedup vs baseline: 1.0179x; 1.0179x over previous
//
#include <hip/hip_runtime.h>
#include <hip/hip_bf16.h>

// Problem constants (from reference)
#define BB 8
#define CC 64
#define OO 64
#define HH 128
#define WW 128
#define HP 130   // padded
#define WP 130
#define KP 9

typedef __attribute__((ext_vector_type(8))) _Float16 f16x8;
typedef __attribute__((ext_vector_type(2))) _Float16 h2;
typedef __attribute__((ext_vector_type(4))) float f32x4;
typedef __attribute__((ext_vector_type(4))) unsigned u32x4;

#define ROWB 16640u   // x_t row stride in bytes = WP*CC*2

static __device__ __forceinline__ unsigned short f2h(float f) {
  _Float16 h = (_Float16)f;
  return __builtin_bit_cast(unsigned short, h);
}
static __device__ __forceinline__ h2 asH2(unsigned u) {
  return __builtin_bit_cast(h2, u);
}
static __device__ __forceinline__ unsigned asU32(h2 v) {
  return __builtin_bit_cast(unsigned, v);
}

// ---------------------------------------------------------------------------
// Kernel 1: x [B][C][H][W] f32 -> x_t [B][HP][WP][C] f16, zero borders.
// XCD-swizzled so XCD k produces x_t[b=k] into its own L2. Blocks 0-143 also
// emit the weight MFMA B-fragments (merged wfrag).
// ---------------------------------------------------------------------------
__global__ __launch_bounds__(256) void k_xpose(const float* __restrict__ x,
                                               const float* __restrict__ wsrc,
                                               unsigned short* __restrict__ xt,
                                               unsigned short* __restrict__ wf) {
  __shared__ unsigned short tile[128][66];
  int wg0 = blockIdx.x;           // B*H = 1024
  int t = threadIdx.x;
  if (wg0 < 144) {
    int flat = wg0 * 256 + t;
    int j = flat & 7;
    int lane = (flat >> 3) & 63;
    int nf = (flat >> 9) & 3;
    int ks = (flat >> 11) & 1;
    int p = flat >> 12;
    int c = ks * 32 + ((lane >> 4) * 8) + j;
    int o = nf * 16 + (lane & 15);
    wf[flat] = f2h(wsrc[(size_t)(o * CC + c) * KP + p]);
  }
  int wg = (wg0 & 7) * 128 + (wg0 >> 3);   // XCD-chunked: XCD k gets b=k
  int h = wg & 127, b = wg >> 7;
  int w = t & 127, chalf = t >> 7;
  const float* xp = x + ((size_t)(b * CC) * HH + h) * WW;
#pragma unroll 4
  for (int c2 = 0; c2 < 32; ++c2) {
    int c = c2 * 2 + chalf;
    float v = xp[(size_t)c * HH * WW + w];
    tile[w][c] = f2h(v);
  }
  __syncthreads();
  int c = t & 63, w2 = t >> 6;
  unsigned short* xtb = xt + (size_t)b * HP * WP * CC;
#pragma unroll 4
  for (int w4 = 0; w4 < 32; ++w4) {
    int ww = w4 * 4 + w2;
    xtb[((size_t)(h + 1) * WP + (ww + 1)) * CC + c] = tile[ww][c];
  }
  if (t < 128) {
    int xx = (t >= 64) ? (WP - 1) : 0;
    xtb[((size_t)(h + 1) * WP + xx) * CC + (t & 63)] = 0;
  }
  if (h == 0) {
    for (int i = t; i < 2 * WP * CC; i += 256) {
      int top = (i < WP * CC);
      int rem = top ? i : i - WP * CC;
      size_t y = top ? 0 : (HP - 1);
      xtb[y * WP * CC + rem] = 0;
    }
  }
}

// ---------------------------------------------------------------------------
// Main kernel (r13 geometry: 256 thr, one wg = (b,h,64-px) x 64 outputs,
// wave w owns outputs [16w,16w+16)). ALL 18 weight fragments are loaded into
// registers in the prologue (72 VGPR) — the p-loop has a trivial ledger:
//   vmcnt(0) drains g(p) -> BUILD -> LOADC(p+1) -> lgkm(0)+bar ->
//   ISSUE g(p+1) -> MFMA(p) with ZERO memory waits.
// f16 sampling path (r13-proven). NO pressure-capping launch_bounds.
// ---------------------------------------------------------------------------
__global__ __launch_bounds__(256) void k_deform_main(const float* __restrict__ offset,
                                                     const float* __restrict__ bias,
                                                     const unsigned short* __restrict__ xt,
                                                     const unsigned short* __restrict__ wf,
                                                     float* __restrict__ out) {
  __shared__ __align__(16) char lds[20992];
  // [0,16384)      S double buffer: 2 x (64 px * 128 B, XOR-swizzled rows)
  // [16384,20992)  coords: 4 waves * 144 entries * 8 B
  // epilogue reuses [0,16640) as S2: f32 [64][65]
  int wg0 = blockIdx.x;                    // 2048
  int wgs = (wg0 & 7) * 256 + (wg0 >> 3);  // XCD k -> b=k
  int tile = wgs & 1, h = (wgs >> 1) & 127, b = wgs >> 8;
  int w0 = tile * 64;
  int t = threadIdx.x, wave = t >> 6, lane = t & 63;

  char* S0 = lds;
  uint2* cw = reinterpret_cast<uint2*>(lds + 16384) + wave * 144;

  // ---- phase 1: coordinate precompute (144 (p,pxl) pairs / wave, 8B packed) ----
  // word0 = corner00 byte offset (22b) | dxflag<<30 | dyflag<<31
  // word1 = f16(wy1) | f16(wx1)<<16   (consumed directly as packed f16)
#pragma unroll
  for (int it = 0; it < 3; ++it) {
    int pair = it * 64 + lane;
    if (pair < 144) {
      int p = pair >> 4, pxl = pair & 15;
      int px = wave * 16 + pxl;
      int w = w0 + px;
      const float* offp = offset + (((size_t)b * 18 + 2 * p) * HH + h) * WW + w;
      float offy = offp[0];
      float offx = offp[HH * WW];
      float cy = (float)(h + p / 3) + offy;
      float cx = (float)(w + p % 3) + offx;
      float y0f = floorf(cy), x0f = floorf(cx);
      float wy1 = cy - y0f, wx1 = cx - x0f;
      int iy0 = (int)y0f, ix0 = (int)x0f;
      int iy0c = min(max(iy0, 0), HP - 1);
      int iy1c = min(max(iy0 + 1, 0), HP - 1);
      int ix0c = min(max(ix0, 0), WP - 1);
      int ix1c = min(max(ix0 + 1, 0), WP - 1);
      unsigned w0p = (unsigned)((iy0c * WP + ix0c) * (CC * 2));
      if (ix1c != ix0c) w0p |= (1u << 30);
      if (iy1c != iy0c) w0p |= (1u << 31);
      unsigned hv;
      asm("v_cvt_pkrtz_f16_f32 %0, %1, %2" : "=v"(hv) : "v"(wy1), "v"(wx1));
      uint2 ce;
      ce.x = w0p;
      ce.y = hv;
      cw[pair] = ce;
    }
  }

  f32x4 acc[4];
#pragma unroll
  for (int m = 0; m < 4; ++m) acc[m] = (f32x4){0.f, 0.f, 0.f, 0.f};

  const char* xb = (const char*)(xt + (size_t)b * HP * WP * CC);
  int c8 = lane & 7, pg = lane >> 3;
  unsigned cb = (unsigned)c8 * 16;              // byte offset of this lane's 8 channels
  unsigned swz = cb ^ ((unsigned)pg << 4);      // write column (XOR row swizzle)
  const uint2* cwl = cw + pg;                   // + p*16 + it*8

#define GLOADX(dst, voff) \
  asm volatile("global_load_dwordx4 %0, %1, %2" \
               : "=v"(dst) : "v"(voff), "s"(xb) : "memory")
#define GLOADW(dst, voff) \
  asm volatile("global_load_dwordx4 %0, %1, %2" \
               : "=v"(dst) : "v"(voff), "s"(wf) : "memory")

  auto LOADC = [&](int p, uint2* eo) {
#pragma unroll
    for (int it = 0; it < 2; ++it) eo[it] = cwl[p * 16 + it * 8];
  };
  auto ISSUE = [&](const uint2* ei, u32x4* go) {
#pragma unroll
    for (int it = 0; it < 2; ++it) {
      unsigned w0p = ei[it].x;
      unsigned a00 = (w0p & 0x003FFFFFu) + cb;
      unsigned dx = ((w0p >> 30) & 1u) << 7;                  // 0 or 128 B (CC*2)
      unsigned dy = (w0p & 0x80000000u) ? ROWB : 0u;          // 0 or 16640
      unsigned a01 = a00 + dx, a10 = a00 + dy, a11 = a10 + dx;
      GLOADX(go[it * 4 + 0], a00);
      GLOADX(go[it * 4 + 1], a01);
      GLOADX(go[it * 4 + 2], a10);
      GLOADX(go[it * 4 + 3], a11);
    }
  };
  auto BUILD = [&](const uint2* ei, const u32x4* gi, char* Sc) {
    char* swave = Sc + wave * 2048 + pg * 128;
#pragma unroll
    for (int it = 0; it < 2; ++it) {
      h2 wyx = asH2(ei[it].y);                 // {wy1, wx1} as f16
      _Float16 wy = wyx.x, wx = wyx.y;
      _Float16 w11 = wy * wx;
      _Float16 w01 = wx - w11;                 // wx*(1-wy)
      _Float16 w10 = wy - w11;                 // wy*(1-wx)
      _Float16 w00 = (_Float16)1.0f - wx - w10;
      h2 W00 = {w00, w00}, W01 = {w01, w01}, W10 = {w10, w10}, W11 = {w11, w11};
      u32x4 q00 = gi[it * 4 + 0], q01 = gi[it * 4 + 1];
      u32x4 q10 = gi[it * 4 + 2], q11 = gi[it * 4 + 3];
      u32x4 pk;
#pragma unroll
      for (int k = 0; k < 4; ++k) {
        h2 s = W00 * asH2(q00[k]) + W01 * asH2(q01[k])
             + W10 * asH2(q10[k]) + W11 * asH2(q11[k]);   // v_pk_mul + 3 v_pk_fma
        pk[k] = asU32(s);
      }
      *reinterpret_cast<u32x4*>(swave + it * 1024 + swz) = pk;
    }
  };
  auto MFMA = [&](const char* Sc, f16x8 b0, f16x8 b1) {
    int l15 = lane & 15, kc = (lane >> 4) * 16, sw = (lane & 7) << 4;
#pragma unroll
    for (int m = 0; m < 4; ++m) {
      int rb = (m * 16 + l15) * 128;
      f16x8 a0 = *reinterpret_cast<const f16x8*>(Sc + rb + (kc ^ sw));
      f16x8 a1 = *reinterpret_cast<const f16x8*>(Sc + rb + ((64 + kc) ^ sw));
      acc[m] = __builtin_amdgcn_mfma_f32_16x16x32_f16(a0, b0, acc[m], 0, 0, 0);
      acc[m] = __builtin_amdgcn_mfma_f32_16x16x32_f16(a1, b1, acc[m], 0, 0, 0);
    }
  };

  // ---- prologue: hoist ALL weight fragments into registers (18 x dwordx4) ----
  f16x8 bw[9][2];
#pragma unroll
  for (int p = 0; p < 9; ++p) {
    unsigned wfo = (unsigned)((p * 8 + wave) * 1024 + lane * 16);
    GLOADW(bw[p][0], wfo);
    GLOADW(bw[p][1], wfo + 4096);
  }
  uint2 e[2];
  u32x4 g[8];
  LOADC(0, e);
  ISSUE(e, g);                     // queue [wf18, g8]

  // ---- pipelined p-loop: single vmcnt(0) per p, MFMA wait-free ----
#pragma unroll
  for (int p = 0; p < 9; ++p) {
    char* Sc = S0 + (p & 1) * 8192;
    asm volatile("s_waitcnt vmcnt(0)" ::: "memory");   // g(p) (and wf at p=0) done
    __builtin_amdgcn_sched_barrier(0);
    BUILD(e, g, Sc);               // consumes g, writes own S slice
    if (p < 8) LOADC(p + 1, e);    // e dead after BUILD — reuse
    // S + coords visible; all waves' MFMA(p-1) LDS reads drained
    asm volatile("s_waitcnt lgkmcnt(0)" ::: "memory");
    __builtin_amdgcn_s_barrier();
    if (p < 8) ISSUE(e, g);        // g(p+1) flies across MFMA(p) + next LOADC
    MFMA(Sc, bw[p][0], bw[p][1]);  // weights already in registers
  }
#undef GLOADX
#undef GLOADW

  // ---- epilogue: LDS transpose for coalesced NCHW stores ----
  __syncthreads();  // all MFMA reads done before overwriting lds as S2
  float* S2 = reinterpret_cast<float*>(lds);
  int l15 = lane & 15;
#pragma unroll
  for (int m = 0; m < 4; ++m) {
#pragma unroll
    for (int i2 = 0; i2 < 4; ++i2) {
      int px = m * 16 + ((lane >> 4) * 4) + i2;
      int o = wave * 16 + l15;
      S2[px * 65 + o] = acc[m][i2];
    }
  }
  __syncthreads();
  {
    int px = t & 63, o2 = t >> 6;
    float* op = out + (((size_t)b * OO) * HH + h) * WW + w0 + px;
#pragma unroll
    for (int o4 = 0; o4 < 16; ++o4) {
      int o = o4 * 4 + o2;
      op[(size_t)o * HH * WW] = S2[px * 65 + o] + bias[o];
    }
  }
}

// ---------------------------------------------------------------------------
extern "C" void kernel_launch(void* const* d_in, const int* in_sizes, int n_in,
                              void* d_out, int out_size, void* d_ws, size_t ws_size,
                              hipStream_t stream) {
  const float* x = (const float*)d_in[0];
  const float* offset = (const float*)d_in[1];
  const float* weight = (const float*)d_in[2];
  const float* bias = (const float*)d_in[3];
  float* out = (float*)d_out;

  unsigned short* xt = (unsigned short*)d_ws;                       // 17,305,600 B
  unsigned short* wf = (unsigned short*)((char*)d_ws + 17305600);   //     73,728 B

  k_xpose<<<BB * HH, 256, 0, stream>>>(x, weight, xt, wf);
  k_deform_main<<<BB * HH * 2, 256, 0, stream>>>(offset, bias, xt, wf, out);
}

// Round 16
// 47.228 us; speedup vs baseline: 1.0645x; 1.0457x over previous
//
#include <hip/hip_runtime.h>
#include <hip/hip_bf16.h>

// Problem constants (from reference)
#define BB 8
#define CC 64
#define OO 64
#define HH 128
#define WW 128
#define HP 130   // padded
#define WP 130
#define KP 9

typedef __attribute__((ext_vector_type(8))) _Float16 f16x8;
typedef __attribute__((ext_vector_type(2))) _Float16 h2;
typedef __attribute__((ext_vector_type(4))) float f32x4;
typedef __attribute__((ext_vector_type(4))) unsigned u32x4;

#define ROWB 16640u   // x_t row stride in bytes = WP*CC*2

static __device__ __forceinline__ unsigned short f2h(float f) {
  _Float16 h = (_Float16)f;
  return __builtin_bit_cast(unsigned short, h);
}
static __device__ __forceinline__ h2 asH2(unsigned u) {
  return __builtin_bit_cast(h2, u);
}
static __device__ __forceinline__ unsigned asU32(h2 v) {
  return __builtin_bit_cast(unsigned, v);
}

// ---------------------------------------------------------------------------
// Kernel 1: x [B][C][H][W] f32 -> x_t [B][HP][WP][C] f16, zero borders.
// XCD-swizzled so XCD k produces x_t[b=k] into its own L2. Blocks 0-143 also
// emit the weight MFMA B-fragments (merged wfrag).
// ---------------------------------------------------------------------------
__global__ __launch_bounds__(256) void k_xpose(const float* __restrict__ x,
                                               const float* __restrict__ wsrc,
                                               unsigned short* __restrict__ xt,
                                               unsigned short* __restrict__ wf) {
  __shared__ unsigned short tile[128][66];
  int wg0 = blockIdx.x;           // B*H = 1024
  int t = threadIdx.x;
  if (wg0 < 144) {
    int flat = wg0 * 256 + t;
    int j = flat & 7;
    int lane = (flat >> 3) & 63;
    int nf = (flat >> 9) & 3;
    int ks = (flat >> 11) & 1;
    int p = flat >> 12;
    int c = ks * 32 + ((lane >> 4) * 8) + j;
    int o = nf * 16 + (lane & 15);
    wf[flat] = f2h(wsrc[(size_t)(o * CC + c) * KP + p]);
  }
  int wg = (wg0 & 7) * 128 + (wg0 >> 3);   // XCD-chunked: XCD k gets b=k
  int h = wg & 127, b = wg >> 7;
  int w = t & 127, chalf = t >> 7;
  const float* xp = x + ((size_t)(b * CC) * HH + h) * WW;
#pragma unroll 4
  for (int c2 = 0; c2 < 32; ++c2) {
    int c = c2 * 2 + chalf;
    float v = xp[(size_t)c * HH * WW + w];
    tile[w][c] = f2h(v);
  }
  __syncthreads();
  int c = t & 63, w2 = t >> 6;
  unsigned short* xtb = xt + (size_t)b * HP * WP * CC;
#pragma unroll 4
  for (int w4 = 0; w4 < 32; ++w4) {
    int ww = w4 * 4 + w2;
    xtb[((size_t)(h + 1) * WP + (ww + 1)) * CC + c] = tile[ww][c];
  }
  if (t < 128) {
    int xx = (t >= 64) ? (WP - 1) : 0;
    xtb[((size_t)(h + 1) * WP + xx) * CC + (t & 63)] = 0;
  }
  if (h == 0) {
    for (int i = t; i < 2 * WP * CC; i += 256) {
      int top = (i < WP * CC);
      int rem = top ? i : i - WP * CC;
      size_t y = top ? 0 : (HP - 1);
      xtb[y * WP * CC + rem] = 0;
    }
  }
}

// ---------------------------------------------------------------------------
// Main kernel (r13 geometry: 256 thr, one wg = (b,h,64-px) x 64 outputs,
// wave w owns outputs [16w,16w+16)). Weights run ONE iteration ahead in a
// ping-pong register pair (+8 VGPR only). Ledger per p (entry [g(p)8, wf(p)2],
// both issued a full phase earlier):
//   vmcnt(0) -> BUILD(p) -> LOADC(p+1) -> lgkm(0)+bar ->
//   ISSUE g(p+1) + GLOADW wf(p+1) -> MFMA(p) WAIT-FREE.
// f16 sampling path (r13-proven). NO pressure-capping launch_bounds
// (allocator must never spill asm-load dsts — r7/r8 lesson).
// ---------------------------------------------------------------------------
__global__ __launch_bounds__(256) void k_deform_main(const float* __restrict__ offset,
                                                     const float* __restrict__ bias,
                                                     const unsigned short* __restrict__ xt,
                                                     const unsigned short* __restrict__ wf,
                                                     float* __restrict__ out) {
  __shared__ __align__(16) char lds[20992];
  // [0,16384)      S double buffer: 2 x (64 px * 128 B, XOR-swizzled rows)
  // [16384,20992)  coords: 4 waves * 144 entries * 8 B
  // epilogue reuses [0,16640) as S2: f32 [64][65]
  int wg0 = blockIdx.x;                    // 2048
  int wgs = (wg0 & 7) * 256 + (wg0 >> 3);  // XCD k -> b=k
  int tile = wgs & 1, h = (wgs >> 1) & 127, b = wgs >> 8;
  int w0 = tile * 64;
  int t = threadIdx.x, wave = t >> 6, lane = t & 63;

  char* S0 = lds;
  uint2* cw = reinterpret_cast<uint2*>(lds + 16384) + wave * 144;

  // ---- phase 1: coordinate precompute (144 (p,pxl) pairs / wave, 8B packed) ----
  // word0 = corner00 byte offset (22b) | dxflag<<30 | dyflag<<31
  // word1 = f16(wy1) | f16(wx1)<<16   (consumed directly as packed f16)
#pragma unroll
  for (int it = 0; it < 3; ++it) {
    int pair = it * 64 + lane;
    if (pair < 144) {
      int p = pair >> 4, pxl = pair & 15;
      int px = wave * 16 + pxl;
      int w = w0 + px;
      const float* offp = offset + (((size_t)b * 18 + 2 * p) * HH + h) * WW + w;
      float offy = offp[0];
      float offx = offp[HH * WW];
      float cy = (float)(h + p / 3) + offy;
      float cx = (float)(w + p % 3) + offx;
      float y0f = floorf(cy), x0f = floorf(cx);
      float wy1 = cy - y0f, wx1 = cx - x0f;
      int iy0 = (int)y0f, ix0 = (int)x0f;
      int iy0c = min(max(iy0, 0), HP - 1);
      int iy1c = min(max(iy0 + 1, 0), HP - 1);
      int ix0c = min(max(ix0, 0), WP - 1);
      int ix1c = min(max(ix0 + 1, 0), WP - 1);
      unsigned w0p = (unsigned)((iy0c * WP + ix0c) * (CC * 2));
      if (ix1c != ix0c) w0p |= (1u << 30);
      if (iy1c != iy0c) w0p |= (1u << 31);
      unsigned hv;
      asm("v_cvt_pkrtz_f16_f32 %0, %1, %2" : "=v"(hv) : "v"(wy1), "v"(wx1));
      uint2 ce;
      ce.x = w0p;
      ce.y = hv;
      cw[pair] = ce;
    }
  }

  f32x4 acc[4];
#pragma unroll
  for (int m = 0; m < 4; ++m) acc[m] = (f32x4){0.f, 0.f, 0.f, 0.f};

  const char* xb = (const char*)(xt + (size_t)b * HP * WP * CC);
  int c8 = lane & 7, pg = lane >> 3;
  unsigned cb = (unsigned)c8 * 16;              // byte offset of this lane's 8 channels
  unsigned swz = cb ^ ((unsigned)pg << 4);      // write column (XOR row swizzle)
  const uint2* cwl = cw + pg;                   // + p*16 + it*8

#define GLOADX(dst, voff) \
  asm volatile("global_load_dwordx4 %0, %1, %2" \
               : "=v"(dst) : "v"(voff), "s"(xb) : "memory")
#define GLOADW(dst, voff) \
  asm volatile("global_load_dwordx4 %0, %1, %2" \
               : "=v"(dst) : "v"(voff), "s"(wf) : "memory")

  auto LOADC = [&](int p, uint2* eo) {
#pragma unroll
    for (int it = 0; it < 2; ++it) eo[it] = cwl[p * 16 + it * 8];
  };
  auto ISSUE = [&](const uint2* ei, u32x4* go) {
#pragma unroll
    for (int it = 0; it < 2; ++it) {
      unsigned w0p = ei[it].x;
      unsigned a00 = (w0p & 0x003FFFFFu) + cb;
      unsigned dx = ((w0p >> 30) & 1u) << 7;                  // 0 or 128 B (CC*2)
      unsigned dy = (w0p & 0x80000000u) ? ROWB : 0u;          // 0 or 16640
      unsigned a01 = a00 + dx, a10 = a00 + dy, a11 = a10 + dx;
      GLOADX(go[it * 4 + 0], a00);
      GLOADX(go[it * 4 + 1], a01);
      GLOADX(go[it * 4 + 2], a10);
      GLOADX(go[it * 4 + 3], a11);
    }
  };
  auto BUILD = [&](const uint2* ei, const u32x4* gi, char* Sc) {
    char* swave = Sc + wave * 2048 + pg * 128;
#pragma unroll
    for (int it = 0; it < 2; ++it) {
      h2 wyx = asH2(ei[it].y);                 // {wy1, wx1} as f16
      _Float16 wy = wyx.x, wx = wyx.y;
      _Float16 w11 = wy * wx;
      _Float16 w01 = wx - w11;                 // wx*(1-wy)
      _Float16 w10 = wy - w11;                 // wy*(1-wx)
      _Float16 w00 = (_Float16)1.0f - wx - w10;
      h2 W00 = {w00, w00}, W01 = {w01, w01}, W10 = {w10, w10}, W11 = {w11, w11};
      u32x4 q00 = gi[it * 4 + 0], q01 = gi[it * 4 + 1];
      u32x4 q10 = gi[it * 4 + 2], q11 = gi[it * 4 + 3];
      u32x4 pk;
#pragma unroll
      for (int k = 0; k < 4; ++k) {
        h2 s = W00 * asH2(q00[k]) + W01 * asH2(q01[k])
             + W10 * asH2(q10[k]) + W11 * asH2(q11[k]);   // v_pk_mul + 3 v_pk_fma
        pk[k] = asU32(s);
      }
      *reinterpret_cast<u32x4*>(swave + it * 1024 + swz) = pk;
    }
  };
  auto MFMA = [&](const char* Sc, f16x8 b0, f16x8 b1) {
    int l15 = lane & 15, kc = (lane >> 4) * 16, sw = (lane & 7) << 4;
#pragma unroll
    for (int m = 0; m < 4; ++m) {
      int rb = (m * 16 + l15) * 128;
      f16x8 a0 = *reinterpret_cast<const f16x8*>(Sc + rb + (kc ^ sw));
      f16x8 a1 = *reinterpret_cast<const f16x8*>(Sc + rb + ((64 + kc) ^ sw));
      acc[m] = __builtin_amdgcn_mfma_f32_16x16x32_f16(a0, b0, acc[m], 0, 0, 0);
      acc[m] = __builtin_amdgcn_mfma_f32_16x16x32_f16(a1, b1, acc[m], 0, 0, 0);
    }
  };

  // ---- prologue: prime queue [g(0)8, wf(0)2] ----
  uint2 e[2];
  u32x4 g[8];
  f16x8 bvA0, bvA1, bvB0, bvB1;
  LOADC(0, e);
  ISSUE(e, g);
  {
    unsigned wfo = (unsigned)((0 * 8 + wave) * 1024 + lane * 16);
    GLOADW(bvA0, wfo);
    GLOADW(bvA1, wfo + 4096);
  }

  // ---- pipelined p-loop: ONE vmcnt(0) per p; MFMA wait-free ----
#pragma unroll
  for (int p = 0; p < 9; ++p) {
    char* Sc = S0 + (p & 1) * 8192;
    // entry queue [g(p)8, wf(p)2] — both issued a full phase earlier
    asm volatile("s_waitcnt vmcnt(0)" ::: "memory");
    __builtin_amdgcn_sched_barrier(0);
    BUILD(e, g, Sc);               // consumes g, writes own S slice
    if (p < 8) LOADC(p + 1, e);    // e dead after BUILD — reuse
    // S + coords visible; all waves' MFMA(p-1) LDS reads drained
    asm volatile("s_waitcnt lgkmcnt(0)" ::: "memory");
    __builtin_amdgcn_s_barrier();
    if (p < 8) {
      ISSUE(e, g);                 // g(p+1) flies across MFMA(p) + next BUILD
      unsigned wfo = (unsigned)(((p + 1) * 8 + wave) * 1024 + lane * 16);
      if (p & 1) { GLOADW(bvA0, wfo); GLOADW(bvA1, wfo + 4096); }
      else       { GLOADW(bvB0, wfo); GLOADW(bvB1, wfo + 4096); }
    }
    // MFMA with this p's weights — already in registers, no wait
    if (p & 1) MFMA(Sc, bvB0, bvB1);
    else       MFMA(Sc, bvA0, bvA1);
  }
#undef GLOADX
#undef GLOADW

  // ---- epilogue: LDS transpose for coalesced NCHW stores ----
  __syncthreads();  // all MFMA reads done before overwriting lds as S2
  float* S2 = reinterpret_cast<float*>(lds);
  int l15 = lane & 15;
#pragma unroll
  for (int m = 0; m < 4; ++m) {
#pragma unroll
    for (int i2 = 0; i2 < 4; ++i2) {
      int px = m * 16 + ((lane >> 4) * 4) + i2;
      int o = wave * 16 + l15;
      S2[px * 65 + o] = acc[m][i2];
    }
  }
  __syncthreads();
  {
    int px = t & 63, o2 = t >> 6;
    float* op = out + (((size_t)b * OO) * HH + h) * WW + w0 + px;
#pragma unroll
    for (int o4 = 0; o4 < 16; ++o4) {
      int o = o4 * 4 + o2;
      op[(size_t)o * HH * WW] = S2[px * 65 + o] + bias[o];
    }
  }
}

// ---------------------------------------------------------------------------
extern "C" void kernel_launch(void* const* d_in, const int* in_sizes, int n_in,
                              void* d_out, int out_size, void* d_ws, size_t ws_size,
                              hipStream_t stream) {
  const float* x = (const float*)d_in[0];
  const float* offset = (const float*)d_in[1];
  const float* weight = (const float*)d_in[2];
  const float* bias = (const float*)d_in[3];
  float* out = (float*)d_out;

  unsigned short* xt = (unsigned short*)d_ws;                       // 17,305,600 B
  unsigned short* wf = (unsigned short*)((char*)d_ws + 17305600);   //     73,728 B

  k_xpose<<<BB * HH, 256, 0, stream>>>(x, weight, xt, wf);
  k_deform_main<<<BB * HH * 2, 256, 0, stream>>>(offset, bias, xt, wf, out);
}

// Round 17
// 46.357 us; speedup vs baseline: 1.0844x; 1.0188x over previous
//
#include <hip/hip_runtime.h>
#include <hip/hip_bf16.h>

// Problem constants (from reference)
#define BB 8
#define CC 64
#define OO 64
#define HH 128
#define WW 128
#define HP 130   // padded
#define WP 130
#define KP 9

typedef __attribute__((ext_vector_type(8))) _Float16 f16x8;
typedef __attribute__((ext_vector_type(2))) _Float16 h2;
typedef __attribute__((ext_vector_type(4))) float f32x4;
typedef __attribute__((ext_vector_type(4))) unsigned u32x4;

#define ROWB 16640u   // x_t row stride in bytes = WP*CC*2

static __device__ __forceinline__ unsigned short f2h(float f) {
  _Float16 h = (_Float16)f;
  return __builtin_bit_cast(unsigned short, h);
}
static __device__ __forceinline__ h2 asH2(unsigned u) {
  return __builtin_bit_cast(h2, u);
}
static __device__ __forceinline__ unsigned asU32(h2 v) {
  return __builtin_bit_cast(unsigned, v);
}

// ---------------------------------------------------------------------------
// Kernel 1: x [B][C][H][W] f32 -> x_t [B][HP][WP][C] f16, zero borders.
// XCD-swizzled so XCD k produces x_t[b=k] into its own L2. Blocks 0-143 also
// emit the weight MFMA B-fragments (merged wfrag).
// ---------------------------------------------------------------------------
__global__ __launch_bounds__(256) void k_xpose(const float* __restrict__ x,
                                               const float* __restrict__ wsrc,
                                               unsigned short* __restrict__ xt,
                                               unsigned short* __restrict__ wf) {
  __shared__ unsigned short tile[128][66];
  int wg0 = blockIdx.x;           // B*H = 1024
  int t = threadIdx.x;
  if (wg0 < 144) {
    int flat = wg0 * 256 + t;
    int j = flat & 7;
    int lane = (flat >> 3) & 63;
    int nf = (flat >> 9) & 3;
    int ks = (flat >> 11) & 1;
    int p = flat >> 12;
    int c = ks * 32 + ((lane >> 4) * 8) + j;
    int o = nf * 16 + (lane & 15);
    wf[flat] = f2h(wsrc[(size_t)(o * CC + c) * KP + p]);
  }
  int wg = (wg0 & 7) * 128 + (wg0 >> 3);   // XCD-chunked: XCD k gets b=k
  int h = wg & 127, b = wg >> 7;
  int w = t & 127, chalf = t >> 7;
  const float* xp = x + ((size_t)(b * CC) * HH + h) * WW;
#pragma unroll 4
  for (int c2 = 0; c2 < 32; ++c2) {
    int c = c2 * 2 + chalf;
    float v = xp[(size_t)c * HH * WW + w];
    tile[w][c] = f2h(v);
  }
  __syncthreads();
  int c = t & 63, w2 = t >> 6;
  unsigned short* xtb = xt + (size_t)b * HP * WP * CC;
#pragma unroll 4
  for (int w4 = 0; w4 < 32; ++w4) {
    int ww = w4 * 4 + w2;
    xtb[((size_t)(h + 1) * WP + (ww + 1)) * CC + c] = tile[ww][c];
  }
  if (t < 128) {
    int xx = (t >= 64) ? (WP - 1) : 0;
    xtb[((size_t)(h + 1) * WP + xx) * CC + (t & 63)] = 0;
  }
  if (h == 0) {
    for (int i = t; i < 2 * WP * CC; i += 256) {
      int top = (i < WP * CC);
      int rem = top ? i : i - WP * CC;
      size_t y = top ? 0 : (HP - 1);
      xtb[y * WP * CC + rem] = 0;
    }
  }
}

// ---------------------------------------------------------------------------
// Main kernel (r16 structure). One change: next-phase loads (g(p+1), wf(p+1))
// are issued BEFORE the lgkm(0)+barrier — they depend only on wave-local
// coords, not on S. Waves issue VMEM while waiting at the barrier, and the
// loads gain the barrier-stall time in flight. Ledger per p (entry
// [g(p)8, wf(p)2], issued a full phase earlier):
//   vmcnt(0) -> BUILD(p) -> LOADC(p+1) -> ISSUE g(p+1)+GLOADW wf(p+1)
//   -> lgkm(0)+bar -> MFMA(p) WAIT-FREE.
// f16 sampling path. NO pressure-capping launch_bounds (r7/r8 lesson).
// ---------------------------------------------------------------------------
__global__ __launch_bounds__(256) void k_deform_main(const float* __restrict__ offset,
                                                     const float* __restrict__ bias,
                                                     const unsigned short* __restrict__ xt,
                                                     const unsigned short* __restrict__ wf,
                                                     float* __restrict__ out) {
  __shared__ __align__(16) char lds[20992];
  // [0,16384)      S double buffer: 2 x (64 px * 128 B, XOR-swizzled rows)
  // [16384,20992)  coords: 4 waves * 144 entries * 8 B
  // epilogue reuses [0,16640) as S2: f32 [64][65]
  int wg0 = blockIdx.x;                    // 2048
  int wgs = (wg0 & 7) * 256 + (wg0 >> 3);  // XCD k -> b=k
  int tile = wgs & 1, h = (wgs >> 1) & 127, b = wgs >> 8;
  int w0 = tile * 64;
  int t = threadIdx.x, wave = t >> 6, lane = t & 63;

  char* S0 = lds;
  uint2* cw = reinterpret_cast<uint2*>(lds + 16384) + wave * 144;

  // ---- phase 1: coordinate precompute (144 (p,pxl) pairs / wave, 8B packed) ----
  // word0 = corner00 byte offset (22b) | dxflag<<30 | dyflag<<31
  // word1 = f16(wy1) | f16(wx1)<<16   (consumed directly as packed f16)
#pragma unroll
  for (int it = 0; it < 3; ++it) {
    int pair = it * 64 + lane;
    if (pair < 144) {
      int p = pair >> 4, pxl = pair & 15;
      int px = wave * 16 + pxl;
      int w = w0 + px;
      const float* offp = offset + (((size_t)b * 18 + 2 * p) * HH + h) * WW + w;
      float offy = offp[0];
      float offx = offp[HH * WW];
      float cy = (float)(h + p / 3) + offy;
      float cx = (float)(w + p % 3) + offx;
      float y0f = floorf(cy), x0f = floorf(cx);
      float wy1 = cy - y0f, wx1 = cx - x0f;
      int iy0 = (int)y0f, ix0 = (int)x0f;
      int iy0c = min(max(iy0, 0), HP - 1);
      int iy1c = min(max(iy0 + 1, 0), HP - 1);
      int ix0c = min(max(ix0, 0), WP - 1);
      int ix1c = min(max(ix0 + 1, 0), WP - 1);
      unsigned w0p = (unsigned)((iy0c * WP + ix0c) * (CC * 2));
      if (ix1c != ix0c) w0p |= (1u << 30);
      if (iy1c != iy0c) w0p |= (1u << 31);
      unsigned hv;
      asm("v_cvt_pkrtz_f16_f32 %0, %1, %2" : "=v"(hv) : "v"(wy1), "v"(wx1));
      uint2 ce;
      ce.x = w0p;
      ce.y = hv;
      cw[pair] = ce;
    }
  }

  f32x4 acc[4];
#pragma unroll
  for (int m = 0; m < 4; ++m) acc[m] = (f32x4){0.f, 0.f, 0.f, 0.f};

  const char* xb = (const char*)(xt + (size_t)b * HP * WP * CC);
  int c8 = lane & 7, pg = lane >> 3;
  unsigned cb = (unsigned)c8 * 16;              // byte offset of this lane's 8 channels
  unsigned swz = cb ^ ((unsigned)pg << 4);      // write column (XOR row swizzle)
  const uint2* cwl = cw + pg;                   // + p*16 + it*8

#define GLOADX(dst, voff) \
  asm volatile("global_load_dwordx4 %0, %1, %2" \
               : "=v"(dst) : "v"(voff), "s"(xb) : "memory")
#define GLOADW(dst, voff) \
  asm volatile("global_load_dwordx4 %0, %1, %2" \
               : "=v"(dst) : "v"(voff), "s"(wf) : "memory")

  auto LOADC = [&](int p, uint2* eo) {
#pragma unroll
    for (int it = 0; it < 2; ++it) eo[it] = cwl[p * 16 + it * 8];
  };
  auto ISSUE = [&](const uint2* ei, u32x4* go) {
#pragma unroll
    for (int it = 0; it < 2; ++it) {
      unsigned w0p = ei[it].x;
      unsigned a00 = (w0p & 0x003FFFFFu) + cb;
      unsigned dx = ((w0p >> 30) & 1u) << 7;                  // 0 or 128 B (CC*2)
      unsigned dy = (w0p & 0x80000000u) ? ROWB : 0u;          // 0 or 16640
      unsigned a01 = a00 + dx, a10 = a00 + dy, a11 = a10 + dx;
      GLOADX(go[it * 4 + 0], a00);
      GLOADX(go[it * 4 + 1], a01);
      GLOADX(go[it * 4 + 2], a10);
      GLOADX(go[it * 4 + 3], a11);
    }
  };
  auto BUILD = [&](const uint2* ei, const u32x4* gi, char* Sc) {
    char* swave = Sc + wave * 2048 + pg * 128;
#pragma unroll
    for (int it = 0; it < 2; ++it) {
      h2 wyx = asH2(ei[it].y);                 // {wy1, wx1} as f16
      _Float16 wy = wyx.x, wx = wyx.y;
      _Float16 w11 = wy * wx;
      _Float16 w01 = wx - w11;                 // wx*(1-wy)
      _Float16 w10 = wy - w11;                 // wy*(1-wx)
      _Float16 w00 = (_Float16)1.0f - wx - w10;
      h2 W00 = {w00, w00}, W01 = {w01, w01}, W10 = {w10, w10}, W11 = {w11, w11};
      u32x4 q00 = gi[it * 4 + 0], q01 = gi[it * 4 + 1];
      u32x4 q10 = gi[it * 4 + 2], q11 = gi[it * 4 + 3];
      u32x4 pk;
#pragma unroll
      for (int k = 0; k < 4; ++k) {
        h2 s = W00 * asH2(q00[k]) + W01 * asH2(q01[k])
             + W10 * asH2(q10[k]) + W11 * asH2(q11[k]);   // v_pk_mul + 3 v_pk_fma
        pk[k] = asU32(s);
      }
      *reinterpret_cast<u32x4*>(swave + it * 1024 + swz) = pk;
    }
  };
  auto MFMA = [&](const char* Sc, f16x8 b0, f16x8 b1) {
    int l15 = lane & 15, kc = (lane >> 4) * 16, sw = (lane & 7) << 4;
#pragma unroll
    for (int m = 0; m < 4; ++m) {
      int rb = (m * 16 + l15) * 128;
      f16x8 a0 = *reinterpret_cast<const f16x8*>(Sc + rb + (kc ^ sw));
      f16x8 a1 = *reinterpret_cast<const f16x8*>(Sc + rb + ((64 + kc) ^ sw));
      acc[m] = __builtin_amdgcn_mfma_f32_16x16x32_f16(a0, b0, acc[m], 0, 0, 0);
      acc[m] = __builtin_amdgcn_mfma_f32_16x16x32_f16(a1, b1, acc[m], 0, 0, 0);
    }
  };

  // ---- prologue: prime queue [g(0)8, wf(0)2] ----
  uint2 e[2];
  u32x4 g[8];
  f16x8 bvA0, bvA1, bvB0, bvB1;
  LOADC(0, e);
  ISSUE(e, g);
  {
    unsigned wfo = (unsigned)((0 * 8 + wave) * 1024 + lane * 16);
    GLOADW(bvA0, wfo);
    GLOADW(bvA1, wfo + 4096);
  }

  // ---- pipelined p-loop: ONE vmcnt(0) per p; next-phase loads issued
  // BEFORE the barrier; MFMA wait-free ----
#pragma unroll
  for (int p = 0; p < 9; ++p) {
    char* Sc = S0 + (p & 1) * 8192;
    // entry queue [g(p)8, wf(p)2] — both issued a full phase earlier
    asm volatile("s_waitcnt vmcnt(0)" ::: "memory");
    __builtin_amdgcn_sched_barrier(0);
    BUILD(e, g, Sc);               // consumes g, writes own S slice
    if (p < 8) {
      LOADC(p + 1, e);             // e dead after BUILD — reuse (wave-local)
      ISSUE(e, g);                 // g(p+1): issued pre-barrier, flies across
                                   // barrier-wait + MFMA(p) + next BUILD
      unsigned wfo = (unsigned)(((p + 1) * 8 + wave) * 1024 + lane * 16);
      if (p & 1) { GLOADW(bvA0, wfo); GLOADW(bvA1, wfo + 4096); }
      else       { GLOADW(bvB0, wfo); GLOADW(bvB1, wfo + 4096); }
    }
    // S writes + coord reads drained; then block-wide barrier
    asm volatile("s_waitcnt lgkmcnt(0)" ::: "memory");
    __builtin_amdgcn_s_barrier();
    // MFMA with this p's weights — already in registers, no wait
    if (p & 1) MFMA(Sc, bvB0, bvB1);
    else       MFMA(Sc, bvA0, bvA1);
  }
#undef GLOADX
#undef GLOADW

  // ---- epilogue: LDS transpose for coalesced NCHW stores ----
  __syncthreads();  // all MFMA reads done before overwriting lds as S2
  float* S2 = reinterpret_cast<float*>(lds);
  int l15 = lane & 15;
#pragma unroll
  for (int m = 0; m < 4; ++m) {
#pragma unroll
    for (int i2 = 0; i2 < 4; ++i2) {
      int px = m * 16 + ((lane >> 4) * 4) + i2;
      int o = wave * 16 + l15;
      S2[px * 65 + o] = acc[m][i2];
    }
  }
  __syncthreads();
  {
    int px = t & 63, o2 = t >> 6;
    float* op = out + (((size_t)b * OO) * HH + h) * WW + w0 + px;
#pragma unroll
    for (int o4 = 0; o4 < 16; ++o4) {
      int o = o4 * 4 + o2;
      op[(size_t)o * HH * WW] = S2[px * 65 + o] + bias[o];
    }
  }
}

// ---------------------------------------------------------------------------
extern "C" void kernel_launch(void* const* d_in, const int* in_sizes, int n_in,
                              void* d_out, int out_size, void* d_ws, size_t ws_size,
                              hipStream_t stream) {
  const float* x = (const float*)d_in[0];
  const float* offset = (const float*)d_in[1];
  const float* weight = (const float*)d_in[2];
  const float* bias = (const float*)d_in[3];
  float* out = (float*)d_out;

  unsigned short* xt = (unsigned short*)d_ws;                       // 17,305,600 B
  unsigned short* wf = (unsigned short*)((char*)d_ws + 17305600);   //     73,728 B

  k_xpose<<<BB * HH, 256, 0, stream>>>(x, weight, xt, wf);
  k_deform_main<<<BB * HH * 2, 256, 0, stream>>>(offset, bias, xt, wf, out);
}